// Round 6
// baseline (192.672 us; speedup 1.0000x reference)
//
#include <hip/hip_runtime.h>

typedef unsigned short u16;
typedef unsigned int   u32;
typedef short bfrag8 __attribute__((ext_vector_type(8)));   // 8 bf16 (raw bits) = 4 VGPRs
typedef float facc4  __attribute__((ext_vector_type(4)));   // MFMA accumulator

#define DIM    1024
#define NH     16
#define HD     64
#define BSZ    4
#define SEQ    2048
#define MROWS  (BSZ*SEQ)      /* 8192 */
#define CHUNK  64
#define NCHUNK (SEQ/CHUNK)    /* 32 */
#define BH     (BSZ*NH)       /* 64 */
#define TS     72             /* transposed-tile LDS row stride (u16) */
#define NT32   32             /* K-tiles (K=1024, BK=32) */

__device__ __forceinline__ u16 f2bf(float f) {
  u32 u = __builtin_bit_cast(u32, f);
  u32 r = u + 0x7fffu + ((u >> 16) & 1u);   // RNE
  return (u16)(r >> 16);
}
__device__ __forceinline__ float bf2f(u16 b) {
  return __builtin_bit_cast(float, (u32)b << 16);
}

__device__ __forceinline__ void gload_lds16(const void* g, void* l) {
  __builtin_amdgcn_global_load_lds((const __attribute__((address_space(1))) u32*)g,
                                   (__attribute__((address_space(3))) u32*)l, 16, 0, 0);
}

// ---------------- prep kernels ----------------

__global__ __launch_bounds__(256) void conv_f32_bf16(const float* __restrict__ in, u16* __restrict__ out) {
  const int i = (blockIdx.x * 256 + threadIdx.x) * 4;
  const float4 v = *(const float4*)(in + i);
  ushort4 o;
  o.x = f2bf(v.x); o.y = f2bf(v.y); o.z = f2bf(v.z); o.w = f2bf(v.w);
  *(ushort4*)(out + i) = o;
}

// Wq' = Wq @ blockdiag(proj), stored TRANSPOSED bf16: wt[(h*64+e)*DIM + i]
__global__ __launch_bounds__(256) void fold_qk(const float* __restrict__ Wq, const float* __restrict__ Wk,
                                               const float* __restrict__ proj, u16* __restrict__ wt) {
  const int i0 = blockIdx.x * 32;
  const int h  = blockIdx.y;
  const int sel = blockIdx.z;           // 0 -> Wq (slot 0), 1 -> Wk (slot 1)
  const float* W = sel ? Wk : Wq;
  u16* out = wt + (size_t)sel * (DIM*DIM);
  __shared__ float sp[64*64];
  __shared__ float sw[32*64];
  const int tid = threadIdx.x;
  for (int idx = tid; idx < 4096; idx += 256) sp[idx] = proj[idx];
  for (int idx = tid; idx < 2048; idx += 256) {
    int r = idx >> 6, c = idx & 63;
    sw[idx] = W[(size_t)(i0 + r)*DIM + h*64 + c];
  }
  __syncthreads();
  const int i  = tid >> 3;
  const int e0 = (tid & 7) * 8;
  #pragma unroll
  for (int ee = 0; ee < 8; ++ee) {
    const int e = e0 + ee;
    float acc = 0.f;
    for (int d = 0; d < 64; ++d) acc += sw[i*64 + d] * sp[d*64 + e];
    out[(size_t)(h*64 + e)*DIM + i0 + i] = f2bf(acc);
  }
}

// transpose + convert: slot2 = Wv^T, slot3 = Wo^T
__global__ __launch_bounds__(256) void trans_conv(const float* __restrict__ Wv, const float* __restrict__ Wo,
                                                  u16* __restrict__ wt) {
  const int sel = blockIdx.z;
  const float* in = sel ? Wo : Wv;
  u16* out = wt + (size_t)(2 + sel) * (DIM*DIM);
  const int n0 = blockIdx.x * 32, k0 = blockIdx.y * 32;
  __shared__ float tile[32][33];
  const int tid = threadIdx.x;
  for (int idx = tid; idx < 1024; idx += 256) {
    int r = idx >> 5, c = idx & 31;
    tile[r][c] = in[(size_t)(k0 + r)*DIM + n0 + c];
  }
  __syncthreads();
  for (int idx = tid; idx < 1024; idx += 256) {
    int r = idx >> 5, c = idx & 31;
    out[(size_t)(n0 + r)*DIM + k0 + c] = f2bf(tile[c][r]);
  }
}

// ---------------- 128x128 BK=32 bf16 MFMA GEMM (m103 structure), C = A @ Wt^T ----------------
// Wt is [N][K] row-major bf16. 256 threads = 4 waves (2M x 2N); per-wave 64x64 output.
// 3 blocks/CU (launch_bounds(256,3); LDS 32 KB dbuf) -> 12 waves/CU of independent-block TLP.
// Stage: 4 gload_lds/thread/tile, issued at loop head into the other buffer; __syncthreads()
// (compiler emits vmcnt/lgkm drain) closes each tile -- the proven m97/m103 pattern.
// Swizzle (even-bank, verified): LDS 16B-slot s of row holds global col-group s ^ ((row>>1)&3);
// a wave's 64 b128 reads cover every bank-quad exactly 8x -> conflict-free.
// Operands swapped (W = MFMA A-operand) so lane regs = 4 consecutive output columns.
// MODE 0: QKV fused over wt rows 0..3071 (elu+1 for sel<2; bf16 out); grid 1536 = 2 rounds @3/CU.
// MODE 1: out GEMM (fp32 out); grid 512 = fully resident.
template<int MODE>
__global__ __launch_bounds__(256, 3)
void gemm128(const u16* __restrict__ A, const u16* __restrict__ W,
             u16* __restrict__ outb, float* __restrict__ outf) {
  __shared__ u16 lds[2][2][4096];   // [buf][0=X,1=W][128 rows * 32 k] = 32 KB
  const int tid  = threadIdx.x;
  const int wave = tid >> 6, lane = tid & 63;
  const int wm = wave >> 1, wn = wave & 1;
  const int lr = lane & 15, g = lane >> 4;

  // bijective XCD swizzle (grid % 8 == 0), n-fastest within each XCD chunk
  const int NY  = (MODE == 0) ? 24 : 8;
  const int q   = (int)gridDim.x >> 3;
  const int bid = (int)blockIdx.x;
  const int nf_ = (bid & 7) * q + (bid >> 3);
  const int m0  = (nf_ / NY) * 128;
  const int ngl = (nf_ % NY) * 128;   // row into Wt (0..3071 / 0..1023)

  // stage tile kt into buffer kt&1: 4 gload_lds per thread (2 X + 2 W)
  auto stage = [&](int kt) {
    #pragma unroll
    for (int o = 0; o < 2; ++o) {
      const int L = o*256 + tid;            // 16B slot 0..511
      const int row = L >> 2, s = L & 3;
      const int gc = ((s ^ ((row >> 1) & 3)) << 3);   // inverse swizzle on global col
      gload_lds16(A + (size_t)(m0  + row)*DIM + kt*32 + gc, &lds[kt & 1][0][(o*256 + wave*64)*8]);
      gload_lds16(W + (size_t)(ngl + row)*DIM + kt*32 + gc, &lds[kt & 1][1][(o*256 + wave*64)*8]);
    }
  };

  stage(0);
  __syncthreads();

  facc4 acc[4][4] = {};   // [nf][mf]

  for (int t = 0; t < NT32; ++t) {
    if (t + 1 < NT32) stage(t + 1);         // issue-early into other buffer
    const u16* lX = &lds[t & 1][0][0];
    const u16* lW = &lds[t & 1][1][0];
    bfrag8 xf[4], wf[4];
    #pragma unroll
    for (int mf = 0; mf < 4; ++mf) {
      const int row = wm*64 + mf*16 + lr;
      xf[mf] = *(const bfrag8*)&lX[row*32 + ((g ^ ((row >> 1) & 3)) << 3)];
    }
    #pragma unroll
    for (int nf = 0; nf < 4; ++nf) {
      const int row = wn*64 + nf*16 + lr;
      wf[nf] = *(const bfrag8*)&lW[row*32 + ((g ^ ((row >> 1) & 3)) << 3)];
    }
    __builtin_amdgcn_s_setprio(1);
    #pragma unroll
    for (int nf = 0; nf < 4; ++nf)
      #pragma unroll
      for (int mf = 0; mf < 4; ++mf)
        acc[nf][mf] = __builtin_amdgcn_mfma_f32_16x16x32_bf16(wf[nf], xf[mf], acc[nf][mf], 0, 0, 0);
    __builtin_amdgcn_s_setprio(0);
    __syncthreads();                        // drains stage(t+1) + closes tile
  }

  // ---- epilogue: lane (lr,g) reg r = out[m = ..+lr][col = ..+g*4+r]
  const int sel = (MODE == 0) ? (ngl >> 10) : 0;
  const bool doElu = (MODE == 0) && (sel < 2);
  const int coly = (MODE == 0) ? (ngl & 1023) : ngl;
  #pragma unroll
  for (int nf = 0; nf < 4; ++nf) {
    #pragma unroll
    for (int mf = 0; mf < 4; ++mf) {
      const facc4 a = acc[nf][mf];
      const int m = m0 + wm*64 + mf*16 + lr;
      const int col0 = coly + wn*64 + nf*16 + g*4;
      float v0 = a[0], v1 = a[1], v2 = a[2], v3 = a[3];
      if (MODE == 0) {
        if (doElu) {
          v0 = (v0 > 0.f) ? (v0 + 1.f) : __expf(v0);
          v1 = (v1 > 0.f) ? (v1 + 1.f) : __expf(v1);
          v2 = (v2 > 0.f) ? (v2 + 1.f) : __expf(v2);
          v3 = (v3 > 0.f) ? (v3 + 1.f) : __expf(v3);
        }
        uint2 pk;
        pk.x = (u32)f2bf(v0) | ((u32)f2bf(v1) << 16);
        pk.y = (u32)f2bf(v2) | ((u32)f2bf(v3) << 16);
        *(uint2*)&outb[(size_t)sel*((size_t)MROWS*DIM) + (size_t)m*DIM + col0] = pk;
      } else {
        float4 pk; pk.x = v0; pk.y = v1; pk.z = v2; pk.w = v3;
        *(float4*)&outf[(size_t)m*DIM + col0] = pk;
      }
    }
  }
}

// ---------------- chunked causal linear-attention scan (MFMA) ----------------
// Ast layout: per (bh, chunk), 64x64 bf16 [e][d] = (K^T V)^T

__global__ __launch_bounds__(256) void phaseA(const u16* __restrict__ Kb, const u16* __restrict__ Vb,
                                              u16* __restrict__ Ast, float* __restrict__ ksum) {
  const int c = blockIdx.x, bh = blockIdx.y;
  const int b = bh >> 4, h = bh & 15;
  const int tid = threadIdx.x;
  const int wave = tid >> 6, lane = tid & 63, lr = lane & 15, g = lane >> 4;
  __shared__ u16 lKt[64*TS];   // lKt[d][t] = K[t][d]
  __shared__ u16 lVt[64*TS];   // lVt[e][t] = V[t][e]
  const size_t mbase = (size_t)b*SEQ + (size_t)c*CHUNK;

  for (int s = tid; s < 512; s += 256) {
    const int t = s >> 3, dg = (s & 7) * 8;
    const bfrag8 kk = *(const bfrag8*)&Kb[(mbase + t)*DIM + h*64 + dg];
    const bfrag8 vv = *(const bfrag8*)&Vb[(mbase + t)*DIM + h*64 + dg];
    #pragma unroll
    for (int j = 0; j < 8; ++j) {
      lKt[(dg + j)*TS + t] = (u16)kk[j];
      lVt[(dg + j)*TS + t] = (u16)vv[j];
    }
  }
  __syncthreads();

  facc4 acc[4] = {};
  #pragma unroll
  for (int kt = 0; kt < 2; ++kt) {
    const bfrag8 af = *(const bfrag8*)&lVt[(wave*16 + lr)*TS + kt*32 + g*8];
    #pragma unroll
    for (int j = 0; j < 4; ++j) {
      const bfrag8 bk = *(const bfrag8*)&lKt[(j*16 + lr)*TS + kt*32 + g*8];
      acc[j] = __builtin_amdgcn_mfma_f32_16x16x32_bf16(af, bk, acc[j], 0, 0, 0);
    }
  }
  u16* dst = Ast + (((size_t)bh*NCHUNK + c) << 12);
  #pragma unroll
  for (int j = 0; j < 4; ++j)
    #pragma unroll
    for (int r = 0; r < 4; ++r)
      dst[(wave*16 + g*4 + r)*64 + j*16 + lr] = f2bf(acc[j][r]);

  const int d = tid >> 2, seg = tid & 3;
  const bfrag8 k0 = *(const bfrag8*)&lKt[d*TS + seg*16];
  const bfrag8 k1 = *(const bfrag8*)&lKt[d*TS + seg*16 + 8];
  float s = 0.f;
  #pragma unroll
  for (int j = 0; j < 8; ++j) s += bf2f((u16)k0[j]) + bf2f((u16)k1[j]);
  s += __shfl_xor(s, 1, 64);
  s += __shfl_xor(s, 2, 64);
  if (seg == 0) ksum[((size_t)bh*NCHUNK + c)*64 + d] = s;
}

__global__ __launch_bounds__(256) void phaseB(u16* __restrict__ Ast, float* __restrict__ ksum) {
  const int bh = blockIdx.x, slice = blockIdx.y;
  const int tid = threadIdx.x;
  u16* base = Ast + (size_t)bh*NCHUNK*4096 + slice*256 + tid;
  float v[NCHUNK];
  #pragma unroll
  for (int c = 0; c < NCHUNK; ++c) v[c] = bf2f(base[(size_t)c*4096]);
  float run = 0.f;
  #pragma unroll
  for (int c = 0; c < NCHUNK; ++c) { base[(size_t)c*4096] = f2bf(run); run += v[c]; }
  if (slice == 0 && tid < 64) {
    float rs = 0.f;
    float* kp = ksum + (size_t)bh*NCHUNK*64 + tid;
    for (int c = 0; c < NCHUNK; ++c) { const float t = kp[c*64]; kp[c*64] = rs; rs += t; }
  }
}

__global__ __launch_bounds__(256) void phaseC(const u16* __restrict__ Qb, const u16* __restrict__ Kb,
                                              const u16* __restrict__ Vb, const u16* __restrict__ Ast,
                                              const float* __restrict__ ksum, u16* __restrict__ Ob) {
  const int c = blockIdx.x, bh = blockIdx.y;
  const int b = bh >> 4, h = bh & 15;
  const int tid = threadIdx.x;
  const int wave = tid >> 6, lane = tid & 63, lr = lane & 15, g = lane >> 4;
  __shared__ u16 lS  [64*TS];
  __shared__ u16 lVt [64*TS];
  __shared__ u16 lKVt[64*TS];
  __shared__ float lks[64];
  __shared__ float lrs[64];
  __shared__ float lqk[64];
  const size_t mbase = (size_t)b*SEQ + (size_t)c*CHUNK;

  for (int s = tid; s < 512; s += 256) {
    const int t = s >> 3, dg = (s & 7) * 8;
    const bfrag8 vv = *(const bfrag8*)&Vb[(mbase + t)*DIM + h*64 + dg];
    #pragma unroll
    for (int j = 0; j < 8; ++j) lVt[(dg + j)*TS + t] = (u16)vv[j];
  }
  const u16* kvsrc = Ast + (((size_t)bh*NCHUNK + c) << 12);
  for (int s = tid; s < 512; s += 256) {
    const int e = s >> 3, dg = (s & 7) * 8;
    *(bfrag8*)&lKVt[e*TS + dg] = *(const bfrag8*)&kvsrc[e*64 + dg];
  }
  if (tid < 64) lks[tid] = ksum[((size_t)bh*NCHUNK + c)*64 + tid];

  bfrag8 qf[2], kf[4][2];
  {
    const u16* qrow = Qb + (mbase + wave*16 + lr)*DIM + h*64;
    qf[0] = *(const bfrag8*)&qrow[g*8];
    qf[1] = *(const bfrag8*)&qrow[32 + g*8];
  }
  #pragma unroll
  for (int j = 0; j < 4; ++j) {
    const u16* krow = Kb + (mbase + j*16 + lr)*DIM + h*64;
    kf[j][0] = *(const bfrag8*)&krow[g*8];
    kf[j][1] = *(const bfrag8*)&krow[32 + g*8];
  }

  facc4 accs[4] = {};
  #pragma unroll
  for (int kt = 0; kt < 2; ++kt)
    #pragma unroll
    for (int j = 0; j < 4; ++j)
      accs[j] = __builtin_amdgcn_mfma_f32_16x16x32_bf16(qf[kt], kf[j][kt], accs[j], 0, 0, 0);

  float rs[4] = {0.f, 0.f, 0.f, 0.f};
  #pragma unroll
  for (int j = 0; j < 4; ++j) {
    const int cc = j*16 + lr;
    #pragma unroll
    for (int r = 0; r < 4; ++r) {
      const int rr = wave*16 + g*4 + r;
      const float vS = (cc <= rr) ? accs[j][r] : 0.f;
      rs[r] += vS;
      lS[rr*TS + cc] = f2bf(vS);
    }
  }
  #pragma unroll
  for (int r = 0; r < 4; ++r) {
    float t = rs[r];
    t += __shfl_xor(t, 1, 64); t += __shfl_xor(t, 2, 64);
    t += __shfl_xor(t, 4, 64); t += __shfl_xor(t, 8, 64);
    if (lr == 0) lrs[wave*16 + g*4 + r] = t;
  }
  __syncthreads();

  {
    const u16* qr2 = Qb + (mbase + wave*16 + lr)*DIM + h*64 + g*16;
    const bfrag8 a0 = *(const bfrag8*)&qr2[0];
    const bfrag8 a1 = *(const bfrag8*)&qr2[8];
    float t = 0.f;
    #pragma unroll
    for (int j = 0; j < 8; ++j)
      t += bf2f((u16)a0[j]) * lks[g*16 + j] + bf2f((u16)a1[j]) * lks[g*16 + 8 + j];
    t += __shfl_xor(t, 16, 64);
    t += __shfl_xor(t, 32, 64);
    if (g == 0) lqk[wave*16 + lr] = t;
  }

  facc4 acco[4] = {};
  #pragma unroll
  for (int kt = 0; kt < 2; ++kt) {
    const bfrag8 sf = *(const bfrag8*)&lS[(wave*16 + lr)*TS + kt*32 + g*8];
    #pragma unroll
    for (int j = 0; j < 4; ++j) {
      const bfrag8 vf = *(const bfrag8*)&lVt[(j*16 + lr)*TS + kt*32 + g*8];
      acco[j] = __builtin_amdgcn_mfma_f32_16x16x32_bf16(sf, vf, acco[j], 0, 0, 0);
    }
  }
  #pragma unroll
  for (int kt = 0; kt < 2; ++kt)
    #pragma unroll
    for (int j = 0; j < 4; ++j) {
      const bfrag8 kvf = *(const bfrag8*)&lKVt[(j*16 + lr)*TS + kt*32 + g*8];
      acco[j] = __builtin_amdgcn_mfma_f32_16x16x32_bf16(qf[kt], kvf, acco[j], 0, 0, 0);
    }

  #pragma unroll
  for (int r = 0; r < 4; ++r) {
    const int rr = wave*16 + g*4 + r;
    const float rden = 1.0f / (lrs[rr] + lqk[rr] + 1e-6f);
    #pragma unroll
    for (int j = 0; j < 4; ++j)
      Ob[(mbase + rr)*DIM + h*64 + j*16 + lr] = f2bf(acco[j][r] * rden);
  }
}

// ---------------- launch ----------------
extern "C" void kernel_launch(void* const* d_in, const int* in_sizes, int n_in,
                              void* d_out, int out_size, void* d_ws, size_t ws_size,
                              hipStream_t stream) {
  const float* x    = (const float*)d_in[0];
  const float* Wq   = (const float*)d_in[1];
  const float* Wk   = (const float*)d_in[2];
  const float* Wv   = (const float*)d_in[3];
  const float* Wo   = (const float*)d_in[4];
  const float* proj = (const float*)d_in[5];
  float* out = (float*)d_out;

  char* ws = (char*)d_ws;
  u16*   xb   = (u16*)  (ws);                       // 16 MB : x in bf16
  u16*   wt   = (u16*)  (ws + 16777216);            //  8 MB : Wq',Wk',Wv^T,Wo^T bf16 (transposed)
  u16*   qkv  = (u16*)  (ws + 25165824);            // 48 MB : Q,K,V bf16 (post feature map)
  u16*   Ob   = (u16*)  (ws + 75497472);            // 16 MB : attention out bf16
  u16*   Ast  = (u16*)  (ws + 92274688);            // 16 MB : chunk KV states bf16 [e][d]
  float* ksum = (float*)(ws + 109051904);           // 512 KB : chunk k-sums fp32
  (void)ws_size; (void)in_sizes; (void)n_in; (void)out_size;

  conv_f32_bf16<<<dim3((MROWS*DIM)/1024), 256, 0, stream>>>(x, xb);
  fold_qk      <<<dim3(DIM/32, NH, 2), 256, 0, stream>>>(Wq, Wk, proj, wt);
  trans_conv   <<<dim3(DIM/32, DIM/32, 2), 256, 0, stream>>>(Wv, Wo, wt);

  // QKV fused: M=8192, N=3072 (wt rows 0..3071 = Wq'|Wk'|Wv^T); 1536 blocks = 2 rounds @ 3/CU
  gemm128<0><<<dim3(64*24), 256, 0, stream>>>(xb, wt, qkv, nullptr);

  const u16* Qb = qkv;
  const u16* Kb = qkv + (size_t)MROWS*DIM;
  const u16* Vb = qkv + 2*(size_t)MROWS*DIM;

  phaseA<<<dim3(NCHUNK, BH), 256, 0, stream>>>(Kb, Vb, Ast, ksum);
  phaseB<<<dim3(BH, 16), 256, 0, stream>>>(Ast, ksum);
  phaseC<<<dim3(NCHUNK, BH), 256, 0, stream>>>(Qb, Kb, Vb, Ast, ksum, Ob);

  // out GEMM: M=8192, N=1024; 512 blocks, all resident
  gemm128<1><<<dim3(64*8), 256, 0, stream>>>(Ob, wt + 3*(size_t)DIM*DIM, nullptr, out);
}

// Round 7
// 189.458 us; speedup vs baseline: 1.0170x; 1.0170x over previous
//
#include <hip/hip_runtime.h>

typedef unsigned short u16;
typedef unsigned int   u32;
typedef short bfrag8 __attribute__((ext_vector_type(8)));   // 8 bf16 (raw bits) = 4 VGPRs
typedef float facc4  __attribute__((ext_vector_type(4)));   // MFMA accumulator

#define DIM    1024
#define NH     16
#define HD     64
#define BSZ    4
#define SEQ    2048
#define MROWS  (BSZ*SEQ)      /* 8192 */
#define CHUNK  64
#define NCHUNK (SEQ/CHUNK)    /* 32 */
#define BH     (BSZ*NH)       /* 64 */
#define TS     72             /* transposed-tile LDS row stride (u16) */
#define NT     16             /* K-tiles per GEMM (K=1024, BK=64) */

__device__ __forceinline__ u16 f2bf(float f) {
  u32 u = __builtin_bit_cast(u32, f);
  u32 r = u + 0x7fffu + ((u >> 16) & 1u);   // RNE
  return (u16)(r >> 16);
}
__device__ __forceinline__ float bf2f(u16 b) {
  return __builtin_bit_cast(float, (u32)b << 16);
}

__device__ __forceinline__ void gload_lds16(const void* g, void* l) {
  __builtin_amdgcn_global_load_lds((const __attribute__((address_space(1))) u32*)g,
                                   (__attribute__((address_space(3))) u32*)l, 16, 0, 0);
}

// ---------------- prep kernels ----------------

__global__ __launch_bounds__(256) void conv_f32_bf16(const float* __restrict__ in, u16* __restrict__ out) {
  const int i = (blockIdx.x * 256 + threadIdx.x) * 4;
  const float4 v = *(const float4*)(in + i);
  ushort4 o;
  o.x = f2bf(v.x); o.y = f2bf(v.y); o.z = f2bf(v.z); o.w = f2bf(v.w);
  *(ushort4*)(out + i) = o;
}

// Wq' = Wq @ blockdiag(proj), stored TRANSPOSED bf16: wt[(h*64+e)*DIM + i]
__global__ __launch_bounds__(256) void fold_qk(const float* __restrict__ Wq, const float* __restrict__ Wk,
                                               const float* __restrict__ proj, u16* __restrict__ wt) {
  const int i0 = blockIdx.x * 32;
  const int h  = blockIdx.y;
  const int sel = blockIdx.z;           // 0 -> Wq (slot 0), 1 -> Wk (slot 1)
  const float* W = sel ? Wk : Wq;
  u16* out = wt + (size_t)sel * (DIM*DIM);
  __shared__ float sp[64*64];
  __shared__ float sw[32*64];
  const int tid = threadIdx.x;
  for (int idx = tid; idx < 4096; idx += 256) sp[idx] = proj[idx];
  for (int idx = tid; idx < 2048; idx += 256) {
    int r = idx >> 6, c = idx & 63;
    sw[idx] = W[(size_t)(i0 + r)*DIM + h*64 + c];
  }
  __syncthreads();
  const int i  = tid >> 3;
  const int e0 = (tid & 7) * 8;
  #pragma unroll
  for (int ee = 0; ee < 8; ++ee) {
    const int e = e0 + ee;
    float acc = 0.f;
    for (int d = 0; d < 64; ++d) acc += sw[i*64 + d] * sp[d*64 + e];
    out[(size_t)(h*64 + e)*DIM + i0 + i] = f2bf(acc);
  }
}

// transpose + convert: slot2 = Wv^T, slot3 = Wo^T
__global__ __launch_bounds__(256) void trans_conv(const float* __restrict__ Wv, const float* __restrict__ Wo,
                                                  u16* __restrict__ wt) {
  const int sel = blockIdx.z;
  const float* in = sel ? Wo : Wv;
  u16* out = wt + (size_t)(2 + sel) * (DIM*DIM);
  const int n0 = blockIdx.x * 32, k0 = blockIdx.y * 32;
  __shared__ float tile[32][33];
  const int tid = threadIdx.x;
  for (int idx = tid; idx < 1024; idx += 256) {
    int r = idx >> 5, c = idx & 31;
    tile[r][c] = in[(size_t)(k0 + r)*DIM + n0 + c];
  }
  __syncthreads();
  for (int idx = tid; idx < 1024; idx += 256) {
    int r = idx >> 5, c = idx & 31;
    out[(size_t)(n0 + r)*DIM + k0 + c] = f2bf(tile[c][r]);
  }
}

// ---------- 128x256 read-ahead pipelined bf16 MFMA GEMM, C = A @ Wt^T ----------
// Wt is [N][K] row-major bf16. 512 threads = 8 waves (2M x 4N). BK=64.
// 3-deep LDS ring (X 16KB x3 + W 32KB x3 = 144 KB). Stage unit = 8KB (1 gload_lds/thr).
// Tile t stages tile t+2 across ph1-3; every unit is drained by a counted vmcnt(8)
// exactly 5 phases after issue (ledger verified; taper 6/4/2/0 in the peeled last pair).
// Phases: 4/tile, 8 MFMA each; ds_reads are ONE PHASE AHEAD into ping-pong frag regs,
// so the compiler's counted lgkmcnt lets MFMA(p) overlap reads(p+1).
// Swizzle (verified, 0 conflicts): slot8 = (kh*4+g) ^ (row&7) on both sides.
// Operands swapped (W = MFMA A-operand) so lane regs = 4 consecutive output columns.
// MODE 0: QKV fused over wt rows 0..3071 (elu+1 for sel<2; bf16 out); grid 768 = 3 rounds.
// MODE 1: out GEMM (fp32 out); grid 256 = 1 round.

#define PH_OPEN() { asm volatile("s_barrier" ::: "memory"); __builtin_amdgcn_sched_barrier(0); \
                    __builtin_amdgcn_s_setprio(1); }
#define PH_CLOSE(VM) { __builtin_amdgcn_s_setprio(0); __builtin_amdgcn_sched_barrier(0); \
                       asm volatile("s_waitcnt vmcnt(" #VM ")" ::: "memory"); \
                       asm volatile("s_barrier" ::: "memory"); }
#define PH_CLOSE0() { __builtin_amdgcn_s_setprio(0); __builtin_amdgcn_sched_barrier(0); \
                      asm volatile("s_barrier" ::: "memory"); }

// stage one 8KB unit (64 rows x 64 k) of tile kt into LDS at dstbase
#define SU(mat, rb, kt, dstbase, seg) \
  gload_lds16((mat) + (size_t)((rb) + (seg)*64 + (tid>>3))*DIM + (kt)*64 + ((((tid)&7) ^ ((tid>>3)&7)) << 3), \
              (dstbase) + (seg)*4096 + tid*8);

#define RDX01(dst, XB) { _Pragma("unroll") for(int mf=0;mf<2;++mf){ _Pragma("unroll") for(int kh=0;kh<2;++kh){ \
  const int row = wm*64 + mf*16 + lr; \
  dst[mf*2+kh] = *(const bfrag8*)&(XB)[row*64 + (((kh*4+g) ^ (row&7)) << 3)]; } } }
#define RDX23(dst, XB) { _Pragma("unroll") for(int mf=0;mf<2;++mf){ _Pragma("unroll") for(int kh=0;kh<2;++kh){ \
  const int row = wm*64 + (2+mf)*16 + lr; \
  dst[mf*2+kh] = *(const bfrag8*)&(XB)[row*64 + (((kh*4+g) ^ (row&7)) << 3)]; } } }
#define RDW01(dst, WB) { _Pragma("unroll") for(int nf=0;nf<2;++nf){ _Pragma("unroll") for(int kh=0;kh<2;++kh){ \
  const int row = wn*32 + nf*16 + lr; \
  dst[nf*2+kh] = *(const bfrag8*)&(WB)[row*64 + (((kh*4+g) ^ (row&7)) << 3)]; } } }
#define RDW23(dst, WB) { _Pragma("unroll") for(int nf=0;nf<2;++nf){ _Pragma("unroll") for(int kh=0;kh<2;++kh){ \
  const int row = 128 + wn*32 + nf*16 + lr; \
  dst[nf*2+kh] = *(const bfrag8*)&(WB)[row*64 + (((kh*4+g) ^ (row&7)) << 3)]; } } }

#define MMQ(NHh, MHh, XF, WF) { \
  _Pragma("unroll") for(int nf=0;nf<2;++nf){ _Pragma("unroll") for(int mf=0;mf<2;++mf){ \
  _Pragma("unroll") for(int kh=0;kh<2;++kh){ \
    acc[(NHh)*2+nf][(MHh)*2+mf] = __builtin_amdgcn_mfma_f32_16x16x32_bf16( \
        WF[nf*2+kh], XF[mf*2+kh], acc[(NHh)*2+nf][(MHh)*2+mf], 0, 0, 0); } } } }

template<int MODE>
__global__ __launch_bounds__(512, 1)
void gemmR(const u16* __restrict__ A, const u16* __restrict__ W,
           u16* __restrict__ outb, float* __restrict__ outf) {
  __shared__ u16 lds[3*8192 + 3*16384];   // X ring | W ring = 144 KB
  u16* ldsX = lds;
  u16* ldsW = lds + 3*8192;
  const int tid  = threadIdx.x;
  const int wave = tid >> 6, lane = tid & 63;
  const int wm = wave >> 2, wn = wave & 3;
  const int lr = lane & 15, g = lane >> 4;

  // bijective XCD swizzle (grid % 8 == 0), n-fastest within each XCD chunk
  const int NY  = (MODE == 0) ? 12 : 4;
  const int q   = (int)gridDim.x >> 3;
  const int bid = (int)blockIdx.x;
  const int nf_ = (bid & 7) * q + (bid >> 3);
  const int m0  = (nf_ / NY) * 128;
  const int ngl = (nf_ % NY) * 256;   // row into Wt (0..3071 / 0..1023)

  // prologue: stage tiles 0 and 1 (order X,Wa,Wb per tile -- matches drain ledger)
  SU(A, m0, 0, ldsX, 0);            SU(A, m0, 0, ldsX, 1);
  SU(W, ngl, 0, ldsW, 0);           SU(W, ngl, 0, ldsW, 1);
  SU(W, ngl, 0, ldsW, 2);           SU(W, ngl, 0, ldsW, 3);
  SU(A, m0, 1, ldsX + 8192, 0);     SU(A, m0, 1, ldsX + 8192, 1);
  SU(W, ngl, 1, ldsW + 16384, 0);   SU(W, ngl, 1, ldsW + 16384, 1);
  SU(W, ngl, 1, ldsW + 16384, 2);   SU(W, ngl, 1, ldsW + 16384, 3);
  asm volatile("s_waitcnt vmcnt(6)" ::: "memory");   // tile 0 resident; tile 1 in flight
  asm volatile("s_barrier" ::: "memory");

  facc4 acc[4][4] = {};   // [nh*2+nf][mh*2+mf]
  bfrag8 xf01a[4], xf23a[4], wf01a[4], wf23a[4];   // even-tile frags
  bfrag8 xf01b[4], xf23b[4], wf01b[4], wf23b[4];   // odd-tile frags

  RDX01(xf01a, ldsX); RDW01(wf01a, ldsW);

  int bE = 0, bO = 1, bS = 2;   // ring slots for tiles E, E+1, E+2
  for (int p = 0; p < 7; ++p) {
    const int E = 2*p;
    const u16* xbE = ldsX + bE*8192;   u16* xbEm = ldsX + bE*8192;
    const u16* wbE = ldsW + bE*16384;  u16* wbEm = ldsW + bE*16384;
    const u16* xbO = ldsX + bO*8192;
    const u16* wbO = ldsW + bO*16384;
    u16* xbS = ldsX + bS*8192;
    u16* wbS = ldsW + bS*16384;
    // ---- tile E ----
    RDX23(xf23a, xbE); SU(A, m0, E+2, xbS, 0); SU(A, m0, E+2, xbS, 1);
    PH_OPEN(); MMQ(0,0,xf01a,wf01a); PH_CLOSE(8);
    RDW23(wf23a, wbE); SU(W, ngl, E+2, wbS, 0); SU(W, ngl, E+2, wbS, 1);
    PH_OPEN(); MMQ(0,1,xf23a,wf01a); PH_CLOSE(8);
    RDX01(xf01b, xbO); SU(W, ngl, E+2, wbS, 2); SU(W, ngl, E+2, wbS, 3);
    PH_OPEN(); MMQ(1,0,xf01a,wf23a); PH_CLOSE(8);
    RDW01(wf01b, wbO);
    PH_OPEN(); MMQ(1,1,xf23a,wf23a); PH_CLOSE0();
    // ---- tile E+1 (stages tile E+3 into E's ring slot -- safe: X(E)/W(E) reads closed) ----
    RDX23(xf23b, xbO); SU(A, m0, E+3, xbEm, 0); SU(A, m0, E+3, xbEm, 1);
    PH_OPEN(); MMQ(0,0,xf01b,wf01b); PH_CLOSE(8);
    RDW23(wf23b, wbO); SU(W, ngl, E+3, wbEm, 0); SU(W, ngl, E+3, wbEm, 1);
    PH_OPEN(); MMQ(0,1,xf23b,wf01b); PH_CLOSE(8);
    RDX01(xf01a, xbS); SU(W, ngl, E+3, wbEm, 2); SU(W, ngl, E+3, wbEm, 3);
    PH_OPEN(); MMQ(1,0,xf01b,wf23b); PH_CLOSE(8);
    RDW01(wf01a, wbS);
    PH_OPEN(); MMQ(1,1,xf23b,wf23b); PH_CLOSE0();
    // rotate ring: (E,O,S) <- (S, E, O)
    const int t_ = bE; bE = bS; bS = bO; bO = t_;
  }
  // ---- peeled last pair: tiles 14,15; no stages; tapered fences 6/4/2/0 ----
  {
    const u16* xbE = ldsX + bE*8192;
    const u16* wbE = ldsW + bE*16384;
    const u16* xbO = ldsX + bO*8192;
    const u16* wbO = ldsW + bO*16384;
    RDX23(xf23a, xbE);
    PH_OPEN(); MMQ(0,0,xf01a,wf01a); PH_CLOSE(6);
    RDW23(wf23a, wbE);
    PH_OPEN(); MMQ(0,1,xf23a,wf01a); PH_CLOSE(4);
    RDX01(xf01b, xbO);
    PH_OPEN(); MMQ(1,0,xf01a,wf23a); PH_CLOSE(2);
    RDW01(wf01b, wbO);
    PH_OPEN(); MMQ(1,1,xf23a,wf23a); PH_CLOSE0();
    RDX23(xf23b, xbO);
    PH_OPEN(); MMQ(0,0,xf01b,wf01b); PH_CLOSE(0);
    RDW23(wf23b, wbO);
    PH_OPEN(); MMQ(0,1,xf23b,wf01b); PH_CLOSE0();
    PH_OPEN(); MMQ(1,0,xf01b,wf23b); PH_CLOSE0();
    PH_OPEN(); MMQ(1,1,xf23b,wf23b);
    __builtin_amdgcn_s_setprio(0);
  }

  // ---- epilogue: lane (lr,g) reg r = out[m = ..+lr][col = ..+g*4+r]
  const int sel = (MODE == 0) ? (ngl >> 10) : 0;
  const bool doElu = (MODE == 0) && (sel < 2);
  const int coly = (MODE == 0) ? (ngl & 1023) : ngl;
  #pragma unroll
  for (int nh = 0; nh < 2; ++nh) {
    #pragma unroll
    for (int nf = 0; nf < 2; ++nf) {
      #pragma unroll
      for (int mf = 0; mf < 4; ++mf) {
        const facc4 a = acc[nh*2+nf][mf];
        const int m = m0 + wm*64 + mf*16 + lr;
        const int col0 = coly + nh*128 + wn*32 + nf*16 + g*4;
        float v0 = a[0], v1 = a[1], v2 = a[2], v3 = a[3];
        if (MODE == 0) {
          if (doElu) {
            v0 = (v0 > 0.f) ? (v0 + 1.f) : __expf(v0);
            v1 = (v1 > 0.f) ? (v1 + 1.f) : __expf(v1);
            v2 = (v2 > 0.f) ? (v2 + 1.f) : __expf(v2);
            v3 = (v3 > 0.f) ? (v3 + 1.f) : __expf(v3);
          }
          uint2 pk;
          pk.x = (u32)f2bf(v0) | ((u32)f2bf(v1) << 16);
          pk.y = (u32)f2bf(v2) | ((u32)f2bf(v3) << 16);
          *(uint2*)&outb[(size_t)sel*((size_t)MROWS*DIM) + (size_t)m*DIM + col0] = pk;
        } else {
          float4 pk; pk.x = v0; pk.y = v1; pk.z = v2; pk.w = v3;
          *(float4*)&outf[(size_t)m*DIM + col0] = pk;
        }
      }
    }
  }
}

// ---------------- chunked causal linear-attention scan (MFMA) ----------------
// Ast layout: per (bh, chunk), 64x64 bf16 [e][d] = (K^T V)^T

__global__ __launch_bounds__(256) void phaseA(const u16* __restrict__ Kb, const u16* __restrict__ Vb,
                                              u16* __restrict__ Ast, float* __restrict__ ksum) {
  const int c = blockIdx.x, bh = blockIdx.y;
  const int b = bh >> 4, h = bh & 15;
  const int tid = threadIdx.x;
  const int wave = tid >> 6, lane = tid & 63, lr = lane & 15, g = lane >> 4;
  __shared__ u16 lKt[64*TS];   // lKt[d][t] = K[t][d]
  __shared__ u16 lVt[64*TS];   // lVt[e][t] = V[t][e]
  const size_t mbase = (size_t)b*SEQ + (size_t)c*CHUNK;

  for (int s = tid; s < 512; s += 256) {
    const int t = s >> 3, dg = (s & 7) * 8;
    const bfrag8 kk = *(const bfrag8*)&Kb[(mbase + t)*DIM + h*64 + dg];
    const bfrag8 vv = *(const bfrag8*)&Vb[(mbase + t)*DIM + h*64 + dg];
    #pragma unroll
    for (int j = 0; j < 8; ++j) {
      lKt[(dg + j)*TS + t] = (u16)kk[j];
      lVt[(dg + j)*TS + t] = (u16)vv[j];
    }
  }
  __syncthreads();

  facc4 acc[4] = {};
  #pragma unroll
  for (int kt = 0; kt < 2; ++kt) {
    const bfrag8 af = *(const bfrag8*)&lVt[(wave*16 + lr)*TS + kt*32 + g*8];
    #pragma unroll
    for (int j = 0; j < 4; ++j) {
      const bfrag8 bk = *(const bfrag8*)&lKt[(j*16 + lr)*TS + kt*32 + g*8];
      acc[j] = __builtin_amdgcn_mfma_f32_16x16x32_bf16(af, bk, acc[j], 0, 0, 0);
    }
  }
  u16* dst = Ast + (((size_t)bh*NCHUNK + c) << 12);
  #pragma unroll
  for (int j = 0; j < 4; ++j)
    #pragma unroll
    for (int r = 0; r < 4; ++r)
      dst[(wave*16 + g*4 + r)*64 + j*16 + lr] = f2bf(acc[j][r]);

  const int d = tid >> 2, seg = tid & 3;
  const bfrag8 k0 = *(const bfrag8*)&lKt[d*TS + seg*16];
  const bfrag8 k1 = *(const bfrag8*)&lKt[d*TS + seg*16 + 8];
  float s = 0.f;
  #pragma unroll
  for (int j = 0; j < 8; ++j) s += bf2f((u16)k0[j]) + bf2f((u16)k1[j]);
  s += __shfl_xor(s, 1, 64);
  s += __shfl_xor(s, 2, 64);
  if (seg == 0) ksum[((size_t)bh*NCHUNK + c)*64 + d] = s;
}

__global__ __launch_bounds__(256) void phaseB(u16* __restrict__ Ast, float* __restrict__ ksum) {
  const int bh = blockIdx.x, slice = blockIdx.y;
  const int tid = threadIdx.x;
  u16* base = Ast + (size_t)bh*NCHUNK*4096 + slice*256 + tid;
  float v[NCHUNK];
  #pragma unroll
  for (int c = 0; c < NCHUNK; ++c) v[c] = bf2f(base[(size_t)c*4096]);
  float run = 0.f;
  #pragma unroll
  for (int c = 0; c < NCHUNK; ++c) { base[(size_t)c*4096] = f2bf(run); run += v[c]; }
  if (slice == 0 && tid < 64) {
    float rs = 0.f;
    float* kp = ksum + (size_t)bh*NCHUNK*64 + tid;
    for (int c = 0; c < NCHUNK; ++c) { const float t = kp[c*64]; kp[c*64] = rs; rs += t; }
  }
}

__global__ __launch_bounds__(256) void phaseC(const u16* __restrict__ Qb, const u16* __restrict__ Kb,
                                              const u16* __restrict__ Vb, const u16* __restrict__ Ast,
                                              const float* __restrict__ ksum, u16* __restrict__ Ob) {
  const int c = blockIdx.x, bh = blockIdx.y;
  const int b = bh >> 4, h = bh & 15;
  const int tid = threadIdx.x;
  const int wave = tid >> 6, lane = tid & 63, lr = lane & 15, g = lane >> 4;
  __shared__ u16 lS  [64*TS];
  __shared__ u16 lVt [64*TS];
  __shared__ u16 lKVt[64*TS];
  __shared__ float lks[64];
  __shared__ float lrs[64];
  __shared__ float lqk[64];
  const size_t mbase = (size_t)b*SEQ + (size_t)c*CHUNK;

  for (int s = tid; s < 512; s += 256) {
    const int t = s >> 3, dg = (s & 7) * 8;
    const bfrag8 vv = *(const bfrag8*)&Vb[(mbase + t)*DIM + h*64 + dg];
    #pragma unroll
    for (int j = 0; j < 8; ++j) lVt[(dg + j)*TS + t] = (u16)vv[j];
  }
  const u16* kvsrc = Ast + (((size_t)bh*NCHUNK + c) << 12);
  for (int s = tid; s < 512; s += 256) {
    const int e = s >> 3, dg = (s & 7) * 8;
    *(bfrag8*)&lKVt[e*TS + dg] = *(const bfrag8*)&kvsrc[e*64 + dg];
  }
  if (tid < 64) lks[tid] = ksum[((size_t)bh*NCHUNK + c)*64 + tid];

  bfrag8 qf[2], kf[4][2];
  {
    const u16* qrow = Qb + (mbase + wave*16 + lr)*DIM + h*64;
    qf[0] = *(const bfrag8*)&qrow[g*8];
    qf[1] = *(const bfrag8*)&qrow[32 + g*8];
  }
  #pragma unroll
  for (int j = 0; j < 4; ++j) {
    const u16* krow = Kb + (mbase + j*16 + lr)*DIM + h*64;
    kf[j][0] = *(const bfrag8*)&krow[g*8];
    kf[j][1] = *(const bfrag8*)&krow[32 + g*8];
  }

  facc4 accs[4] = {};
  #pragma unroll
  for (int kt = 0; kt < 2; ++kt)
    #pragma unroll
    for (int j = 0; j < 4; ++j)
      accs[j] = __builtin_amdgcn_mfma_f32_16x16x32_bf16(qf[kt], kf[j][kt], accs[j], 0, 0, 0);

  float rs[4] = {0.f, 0.f, 0.f, 0.f};
  #pragma unroll
  for (int j = 0; j < 4; ++j) {
    const int cc = j*16 + lr;
    #pragma unroll
    for (int r = 0; r < 4; ++r) {
      const int rr = wave*16 + g*4 + r;
      const float vS = (cc <= rr) ? accs[j][r] : 0.f;
      rs[r] += vS;
      lS[rr*TS + cc] = f2bf(vS);
    }
  }
  #pragma unroll
  for (int r = 0; r < 4; ++r) {
    float t = rs[r];
    t += __shfl_xor(t, 1, 64); t += __shfl_xor(t, 2, 64);
    t += __shfl_xor(t, 4, 64); t += __shfl_xor(t, 8, 64);
    if (lr == 0) lrs[wave*16 + g*4 + r] = t;
  }
  __syncthreads();

  {
    const u16* qr2 = Qb + (mbase + wave*16 + lr)*DIM + h*64 + g*16;
    const bfrag8 a0 = *(const bfrag8*)&qr2[0];
    const bfrag8 a1 = *(const bfrag8*)&qr2[8];
    float t = 0.f;
    #pragma unroll
    for (int j = 0; j < 8; ++j)
      t += bf2f((u16)a0[j]) * lks[g*16 + j] + bf2f((u16)a1[j]) * lks[g*16 + 8 + j];
    t += __shfl_xor(t, 16, 64);
    t += __shfl_xor(t, 32, 64);
    if (g == 0) lqk[wave*16 + lr] = t;
  }

  facc4 acco[4] = {};
  #pragma unroll
  for (int kt = 0; kt < 2; ++kt) {
    const bfrag8 sf = *(const bfrag8*)&lS[(wave*16 + lr)*TS + kt*32 + g*8];
    #pragma unroll
    for (int j = 0; j < 4; ++j) {
      const bfrag8 vf = *(const bfrag8*)&lVt[(j*16 + lr)*TS + kt*32 + g*8];
      acco[j] = __builtin_amdgcn_mfma_f32_16x16x32_bf16(sf, vf, acco[j], 0, 0, 0);
    }
  }
  #pragma unroll
  for (int kt = 0; kt < 2; ++kt)
    #pragma unroll
    for (int j = 0; j < 4; ++j) {
      const bfrag8 kvf = *(const bfrag8*)&lKVt[(j*16 + lr)*TS + kt*32 + g*8];
      acco[j] = __builtin_amdgcn_mfma_f32_16x16x32_bf16(qf[kt], kvf, acco[j], 0, 0, 0);
    }

  #pragma unroll
  for (int r = 0; r < 4; ++r) {
    const int rr = wave*16 + g*4 + r;
    const float rden = 1.0f / (lrs[rr] + lqk[rr] + 1e-6f);
    #pragma unroll
    for (int j = 0; j < 4; ++j)
      Ob[(mbase + rr)*DIM + h*64 + j*16 + lr] = f2bf(acco[j][r] * rden);
  }
}

// ---------------- launch ----------------
extern "C" void kernel_launch(void* const* d_in, const int* in_sizes, int n_in,
                              void* d_out, int out_size, void* d_ws, size_t ws_size,
                              hipStream_t stream) {
  const float* x    = (const float*)d_in[0];
  const float* Wq   = (const float*)d_in[1];
  const float* Wk   = (const float*)d_in[2];
  const float* Wv   = (const float*)d_in[3];
  const float* Wo   = (const float*)d_in[4];
  const float* proj = (const float*)d_in[5];
  float* out = (float*)d_out;

  char* ws = (char*)d_ws;
  u16*   xb   = (u16*)  (ws);                       // 16 MB : x in bf16
  u16*   wt   = (u16*)  (ws + 16777216);            //  8 MB : Wq',Wk',Wv^T,Wo^T bf16 (transposed)
  u16*   qkv  = (u16*)  (ws + 25165824);            // 48 MB : Q,K,V bf16 (post feature map)
  u16*   Ob   = (u16*)  (ws + 75497472);            // 16 MB : attention out bf16
  u16*   Ast  = (u16*)  (ws + 92274688);            // 16 MB : chunk KV states bf16 [e][d]
  float* ksum = (float*)(ws + 109051904);           // 512 KB : chunk k-sums fp32
  (void)ws_size; (void)in_sizes; (void)n_in; (void)out_size;

  conv_f32_bf16<<<dim3((MROWS*DIM)/1024), 256, 0, stream>>>(x, xb);
  fold_qk      <<<dim3(DIM/32, NH, 2), 256, 0, stream>>>(Wq, Wk, proj, wt);
  trans_conv   <<<dim3(DIM/32, DIM/32, 2), 256, 0, stream>>>(Wv, Wo, wt);

  // QKV fused: M=8192, N=3072 (wt rows 0..3071 = Wq'|Wk'|Wv^T); 768 blocks = 3 exact rounds
  gemmR<0><<<dim3(64*12), 512, 0, stream>>>(xb, wt, qkv, nullptr);

  const u16* Qb = qkv;
  const u16* Kb = qkv + (size_t)MROWS*DIM;
  const u16* Vb = qkv + 2*(size_t)MROWS*DIM;

  phaseA<<<dim3(NCHUNK, BH), 256, 0, stream>>>(Kb, Vb, Ast, ksum);
  phaseB<<<dim3(BH, 16), 256, 0, stream>>>(Ast, ksum);
  phaseC<<<dim3(NCHUNK, BH), 256, 0, stream>>>(Qb, Kb, Vb, Ast, ksum, Ob);

  // out GEMM: M=8192, N=1024; 256 blocks = 1 exact round
  gemmR<1><<<dim3(64*4), 512, 0, stream>>>(Ob, wt + 3*(size_t)DIM*DIM, nullptr, out);
}

// Round 8
// 185.046 us; speedup vs baseline: 1.0412x; 1.0238x over previous
//
#include <hip/hip_runtime.h>

typedef unsigned short u16;
typedef unsigned int   u32;
typedef short bfrag8 __attribute__((ext_vector_type(8)));   // 8 bf16 (raw bits) = 4 VGPRs
typedef float facc4  __attribute__((ext_vector_type(4)));   // MFMA accumulator

#define DIM    1024
#define NH     16
#define HD     64
#define BSZ    4
#define SEQ    2048
#define MROWS  (BSZ*SEQ)      /* 8192 */
#define CHUNK  64
#define NCHUNK (SEQ/CHUNK)    /* 32 */
#define BH     (BSZ*NH)       /* 64 */
#define TS     72             /* transposed-tile LDS row stride (u16) */
#define NT     16             /* K-tiles per GEMM (K=1024, BK=64) */

__device__ __forceinline__ u16 f2bf(float f) {
  u32 u = __builtin_bit_cast(u32, f);
  u32 r = u + 0x7fffu + ((u >> 16) & 1u);   // RNE
  return (u16)(r >> 16);
}
__device__ __forceinline__ float bf2f(u16 b) {
  return __builtin_bit_cast(float, (u32)b << 16);
}

__device__ __forceinline__ void gload_lds16(const void* g, void* l) {
  __builtin_amdgcn_global_load_lds((const __attribute__((address_space(1))) u32*)g,
                                   (__attribute__((address_space(3))) u32*)l, 16, 0, 0);
}

// ---------------- prep kernels ----------------

__global__ __launch_bounds__(256) void conv_f32_bf16(const float* __restrict__ in, u16* __restrict__ out) {
  const int i = (blockIdx.x * 256 + threadIdx.x) * 4;
  const float4 v = *(const float4*)(in + i);
  ushort4 o;
  o.x = f2bf(v.x); o.y = f2bf(v.y); o.z = f2bf(v.z); o.w = f2bf(v.w);
  *(ushort4*)(out + i) = o;
}

// Wq' = Wq @ blockdiag(proj), stored TRANSPOSED bf16: wt[(h*64+e)*DIM + i]
__global__ __launch_bounds__(256) void fold_qk(const float* __restrict__ Wq, const float* __restrict__ Wk,
                                               const float* __restrict__ proj, u16* __restrict__ wt) {
  const int i0 = blockIdx.x * 32;
  const int h  = blockIdx.y;
  const int sel = blockIdx.z;           // 0 -> Wq (slot 0), 1 -> Wk (slot 1)
  const float* W = sel ? Wk : Wq;
  u16* out = wt + (size_t)sel * (DIM*DIM);
  __shared__ float sp[64*64];
  __shared__ float sw[32*64];
  const int tid = threadIdx.x;
  for (int idx = tid; idx < 4096; idx += 256) sp[idx] = proj[idx];
  for (int idx = tid; idx < 2048; idx += 256) {
    int r = idx >> 6, c = idx & 63;
    sw[idx] = W[(size_t)(i0 + r)*DIM + h*64 + c];
  }
  __syncthreads();
  const int i  = tid >> 3;
  const int e0 = (tid & 7) * 8;
  #pragma unroll
  for (int ee = 0; ee < 8; ++ee) {
    const int e = e0 + ee;
    float acc = 0.f;
    for (int d = 0; d < 64; ++d) acc += sw[i*64 + d] * sp[d*64 + e];
    out[(size_t)(h*64 + e)*DIM + i0 + i] = f2bf(acc);
  }
}

// transpose + convert: slot2 = Wv^T, slot3 = Wo^T
__global__ __launch_bounds__(256) void trans_conv(const float* __restrict__ Wv, const float* __restrict__ Wo,
                                                  u16* __restrict__ wt) {
  const int sel = blockIdx.z;
  const float* in = sel ? Wo : Wv;
  u16* out = wt + (size_t)(2 + sel) * (DIM*DIM);
  const int n0 = blockIdx.x * 32, k0 = blockIdx.y * 32;
  __shared__ float tile[32][33];
  const int tid = threadIdx.x;
  for (int idx = tid; idx < 1024; idx += 256) {
    int r = idx >> 5, c = idx & 31;
    tile[r][c] = in[(size_t)(k0 + r)*DIM + n0 + c];
  }
  __syncthreads();
  for (int idx = tid; idx < 1024; idx += 256) {
    int r = idx >> 5, c = idx & 31;
    out[(size_t)(n0 + r)*DIM + k0 + c] = f2bf(tile[c][r]);
  }
}

// ---------- 128x256 2-phase full-read-ahead bf16 MFMA GEMM, C = A @ Wt^T ----------
// Same geometry/swizzle/grids as r5/r7; schedule rebuilt:
//  - 2 phases/K-tile, 16 MFMA each (A: N-half 0, B: N-half 1)
//  - reads one FULL phase ahead: {xf(t+1), wf01(t+1)} during B(t); wf23(t) during A(t);
//    the lone lgkmcnt(0) (A-open) waits on reads issued a whole MFMA-phase earlier.
//  - 2 barriers + 1 counted vmcnt per tile. close-A vmcnt(2) certifies tile t+1's 6
//    stage-ops (leaves X(t+2)'s 2 in flight). Ring-3 LDS: stage slot never collides
//    with a read slot; every overwrite is >= 1 barrier after read certification.
// MODE 0: QKV fused over wt rows 0..3071 (elu+1 for sel<2; bf16 out); grid 768 = 3 rounds.
// MODE 1: out GEMM (fp32 out); grid 256 = 1 round.

#define SBAR0() __builtin_amdgcn_sched_barrier(0)
#define OPA()   { asm volatile("s_waitcnt lgkmcnt(0)" ::: "memory"); SBAR0(); }
#define MID(VM) { SBAR0(); asm volatile("s_waitcnt vmcnt(" #VM ")" ::: "memory"); \
                  asm volatile("s_barrier" ::: "memory"); }
#define ENDB()  { SBAR0(); asm volatile("s_barrier" ::: "memory"); }

// stage one 8KB unit (64 rows x 64 k) of tile kt into LDS at dstbase
#define SU(mat, rb, kt, dstbase, seg) \
  gload_lds16((mat) + (size_t)((rb) + (seg)*64 + (tid>>3))*DIM + (kt)*64 + ((((tid)&7) ^ ((tid>>3)&7)) << 3), \
              (dstbase) + (seg)*4096 + tid*8);

#define RD_X8(dst, XB) { _Pragma("unroll") for(int mf=0;mf<4;++mf){ _Pragma("unroll") for(int kh=0;kh<2;++kh){ \
  const int row = wm*64 + mf*16 + lr; \
  dst[mf*2+kh] = *(const bfrag8*)&(XB)[row*64 + (((kh*4+g) ^ (row&7)) << 3)]; } } }
#define RD_W01(dst, WB) { _Pragma("unroll") for(int nf=0;nf<2;++nf){ _Pragma("unroll") for(int kh=0;kh<2;++kh){ \
  const int row = wn*32 + nf*16 + lr; \
  dst[nf*2+kh] = *(const bfrag8*)&(WB)[row*64 + (((kh*4+g) ^ (row&7)) << 3)]; } } }
#define RD_W23(dst, WB) { _Pragma("unroll") for(int nf=0;nf<2;++nf){ _Pragma("unroll") for(int kh=0;kh<2;++kh){ \
  const int row = 128 + wn*32 + nf*16 + lr; \
  dst[nf*2+kh] = *(const bfrag8*)&(WB)[row*64 + (((kh*4+g) ^ (row&7)) << 3)]; } } }

#define MMH(NHh, WF, XF) { __builtin_amdgcn_s_setprio(1); \
  _Pragma("unroll") for(int nf=0;nf<2;++nf){ _Pragma("unroll") for(int mf=0;mf<4;++mf){ \
  _Pragma("unroll") for(int kh=0;kh<2;++kh){ \
    acc[(NHh)*2+nf][mf] = __builtin_amdgcn_mfma_f32_16x16x32_bf16( \
        WF[nf*2+kh], XF[mf*2+kh], acc[(NHh)*2+nf][mf], 0, 0, 0); } } } \
  __builtin_amdgcn_s_setprio(0); }

template<int MODE>
__global__ __launch_bounds__(512, 1)
void gemmP(const u16* __restrict__ A, const u16* __restrict__ W,
           u16* __restrict__ outb, float* __restrict__ outf) {
  __shared__ u16 lds[3*8192 + 3*16384];   // X ring (3x16KB) | W ring (3x32KB) = 144 KB
  u16* ldsX = lds;
  u16* ldsW = lds + 3*8192;
  const int tid  = threadIdx.x;
  const int wave = tid >> 6, lane = tid & 63;
  const int wm = wave >> 2, wn = wave & 3;
  const int lr = lane & 15, g = lane >> 4;

  // bijective XCD swizzle (grid % 8 == 0), n-fastest within each XCD chunk
  const int NY  = (MODE == 0) ? 12 : 4;
  const int q   = (int)gridDim.x >> 3;
  const int bid = (int)blockIdx.x;
  const int nf_ = (bid & 7) * q + (bid >> 3);
  const int m0  = (nf_ / NY) * 128;
  const int ngl = (nf_ % NY) * 256;   // row into Wt (0..3071 / 0..1023)

  // prologue: stage tiles 0 and 1
  SU(A, m0, 0, ldsX, 0);            SU(A, m0, 0, ldsX, 1);
  SU(W, ngl, 0, ldsW, 0);           SU(W, ngl, 0, ldsW, 1);
  SU(W, ngl, 0, ldsW, 2);           SU(W, ngl, 0, ldsW, 3);
  SU(A, m0, 1, ldsX + 8192, 0);     SU(A, m0, 1, ldsX + 8192, 1);
  SU(W, ngl, 1, ldsW + 16384, 0);   SU(W, ngl, 1, ldsW + 16384, 1);
  SU(W, ngl, 1, ldsW + 16384, 2);   SU(W, ngl, 1, ldsW + 16384, 3);
  asm volatile("s_waitcnt vmcnt(6)" ::: "memory");   // tile 0 resident; tile 1 in flight
  asm volatile("s_barrier" ::: "memory");

  facc4 acc[4][4] = {};   // [nh*2+nf][mf]
  bfrag8 xfa[8], w01a[4], w23a[4];   // even-tile frags
  bfrag8 xfb[8], w01b[4], w23b[4];   // odd-tile frags

  RD_X8(xfa, ldsX); RD_W01(w01a, ldsW);   // tile 0 main frags

  int bE = 0, bO = 1, bS = 2;   // ring slots for tiles E, E+1, E+2
  for (int p = 0; p < 7; ++p) {
    const int E = 2*p;
    u16* xE = ldsX + bE*8192;   u16* wE = ldsW + bE*16384;
    u16* xO = ldsX + bO*8192;   u16* wO = ldsW + bO*16384;
    u16* xS = ldsX + bS*8192;   u16* wS = ldsW + bS*16384;
    // ---- A(E): uses {xfa, w01a}; read wf23(E); stage X(E+2)->slotS ----
    OPA();
    RD_W23(w23a, wE);
    SU(A, m0, E+2, xS, 0); SU(A, m0, E+2, xS, 1);
    SBAR0();
    MMH(0, w01a, xfa);
    MID(2);            // certify tile E+1 stages (X(E+2) stays in flight)
    // ---- B(E): uses {xfa, w23a}; read tile E+1 main frags; stage W(E+2)->slotS ----
    RD_X8(xfb, xO); RD_W01(w01b, wO);
    SU(W, ngl, E+2, wS, 0); SU(W, ngl, E+2, wS, 1);
    SU(W, ngl, E+2, wS, 2); SU(W, ngl, E+2, wS, 3);
    SBAR0();
    MMH(1, w23a, xfa);
    ENDB();
    // ---- A(E+1): uses {xfb, w01b}; read wf23(E+1); stage X(E+3)->slotE ----
    OPA();
    RD_W23(w23b, wO);
    SU(A, m0, E+3, xE, 0); SU(A, m0, E+3, xE, 1);
    SBAR0();
    MMH(0, w01b, xfb);
    MID(2);            // certify tile E+2 stages
    // ---- B(E+1): read tile E+2 main frags; stage W(E+3)->slotE ----
    RD_X8(xfa, xS); RD_W01(w01a, wS);
    SU(W, ngl, E+3, wE, 0); SU(W, ngl, E+3, wE, 1);
    SU(W, ngl, E+3, wE, 2); SU(W, ngl, E+3, wE, 3);
    SBAR0();
    MMH(1, w23b, xfb);
    ENDB();
    // rotate ring: (E,O,S) <- (S, E, O)
    const int t_ = bE; bE = bS; bS = bO; bO = t_;
  }
  // ---- peeled tiles 14 (set a), 15 (set b): no stages ----
  {
    u16* wE = ldsW + bE*16384;
    u16* xO = ldsX + bO*8192;   u16* wO = ldsW + bO*16384;
    // A(14)
    OPA();
    RD_W23(w23a, wE);
    SBAR0();
    MMH(0, w01a, xfa);
    MID(0);            // drain tile-15 stages
    // B(14): read tile-15 frags
    RD_X8(xfb, xO); RD_W01(w01b, wO);
    SBAR0();
    MMH(1, w23a, xfa);
    ENDB();
    // A(15)
    OPA();
    RD_W23(w23b, wO);
    SBAR0();
    MMH(0, w01b, xfb);
    ENDB();
    // B(15)
    MMH(1, w23b, xfb);
  }

  // ---- epilogue: lane (lr,g) reg r = out[m = ..+lr][col = ..+g*4+r]
  const int sel = (MODE == 0) ? (ngl >> 10) : 0;
  const bool doElu = (MODE == 0) && (sel < 2);
  const int coly = (MODE == 0) ? (ngl & 1023) : ngl;
  #pragma unroll
  for (int nh = 0; nh < 2; ++nh) {
    #pragma unroll
    for (int nf = 0; nf < 2; ++nf) {
      #pragma unroll
      for (int mf = 0; mf < 4; ++mf) {
        const facc4 a = acc[nh*2+nf][mf];
        const int m = m0 + wm*64 + mf*16 + lr;
        const int col0 = coly + nh*128 + wn*32 + nf*16 + g*4;
        float v0 = a[0], v1 = a[1], v2 = a[2], v3 = a[3];
        if (MODE == 0) {
          if (doElu) {
            v0 = (v0 > 0.f) ? (v0 + 1.f) : __expf(v0);
            v1 = (v1 > 0.f) ? (v1 + 1.f) : __expf(v1);
            v2 = (v2 > 0.f) ? (v2 + 1.f) : __expf(v2);
            v3 = (v3 > 0.f) ? (v3 + 1.f) : __expf(v3);
          }
          uint2 pk;
          pk.x = (u32)f2bf(v0) | ((u32)f2bf(v1) << 16);
          pk.y = (u32)f2bf(v2) | ((u32)f2bf(v3) << 16);
          *(uint2*)&outb[(size_t)sel*((size_t)MROWS*DIM) + (size_t)m*DIM + col0] = pk;
        } else {
          float4 pk; pk.x = v0; pk.y = v1; pk.z = v2; pk.w = v3;
          *(float4*)&outf[(size_t)m*DIM + col0] = pk;
        }
      }
    }
  }
}

// ---------------- chunked causal linear-attention scan (MFMA) ----------------
// Ast layout: per (bh, chunk), 64x64 bf16 [e][d] = (K^T V)^T

__global__ __launch_bounds__(256) void phaseA(const u16* __restrict__ Kb, const u16* __restrict__ Vb,
                                              u16* __restrict__ Ast, float* __restrict__ ksum) {
  const int c = blockIdx.x, bh = blockIdx.y;
  const int b = bh >> 4, h = bh & 15;
  const int tid = threadIdx.x;
  const int wave = tid >> 6, lane = tid & 63, lr = lane & 15, g = lane >> 4;
  __shared__ u16 lKt[64*TS];   // lKt[d][t] = K[t][d]
  __shared__ u16 lVt[64*TS];   // lVt[e][t] = V[t][e]
  const size_t mbase = (size_t)b*SEQ + (size_t)c*CHUNK;

  for (int s = tid; s < 512; s += 256) {
    const int t = s >> 3, dg = (s & 7) * 8;
    const bfrag8 kk = *(const bfrag8*)&Kb[(mbase + t)*DIM + h*64 + dg];
    const bfrag8 vv = *(const bfrag8*)&Vb[(mbase + t)*DIM + h*64 + dg];
    #pragma unroll
    for (int j = 0; j < 8; ++j) {
      lKt[(dg + j)*TS + t] = (u16)kk[j];
      lVt[(dg + j)*TS + t] = (u16)vv[j];
    }
  }
  __syncthreads();

  facc4 acc[4] = {};
  #pragma unroll
  for (int kt = 0; kt < 2; ++kt) {
    const bfrag8 af = *(const bfrag8*)&lVt[(wave*16 + lr)*TS + kt*32 + g*8];
    #pragma unroll
    for (int j = 0; j < 4; ++j) {
      const bfrag8 bk = *(const bfrag8*)&lKt[(j*16 + lr)*TS + kt*32 + g*8];
      acc[j] = __builtin_amdgcn_mfma_f32_16x16x32_bf16(af, bk, acc[j], 0, 0, 0);
    }
  }
  u16* dst = Ast + (((size_t)bh*NCHUNK + c) << 12);
  #pragma unroll
  for (int j = 0; j < 4; ++j)
    #pragma unroll
    for (int r = 0; r < 4; ++r)
      dst[(wave*16 + g*4 + r)*64 + j*16 + lr] = f2bf(acc[j][r]);

  const int d = tid >> 2, seg = tid & 3;
  const bfrag8 k0 = *(const bfrag8*)&lKt[d*TS + seg*16];
  const bfrag8 k1 = *(const bfrag8*)&lKt[d*TS + seg*16 + 8];
  float s = 0.f;
  #pragma unroll
  for (int j = 0; j < 8; ++j) s += bf2f((u16)k0[j]) + bf2f((u16)k1[j]);
  s += __shfl_xor(s, 1, 64);
  s += __shfl_xor(s, 2, 64);
  if (seg == 0) ksum[((size_t)bh*NCHUNK + c)*64 + d] = s;
}

__global__ __launch_bounds__(256) void phaseB(u16* __restrict__ Ast, float* __restrict__ ksum) {
  const int bh = blockIdx.x, slice = blockIdx.y;
  const int tid = threadIdx.x;
  u16* base = Ast + (size_t)bh*NCHUNK*4096 + slice*256 + tid;
  float v[NCHUNK];
  #pragma unroll
  for (int c = 0; c < NCHUNK; ++c) v[c] = bf2f(base[(size_t)c*4096]);
  float run = 0.f;
  #pragma unroll
  for (int c = 0; c < NCHUNK; ++c) { base[(size_t)c*4096] = f2bf(run); run += v[c]; }
  if (slice == 0 && tid < 64) {
    float rs = 0.f;
    float* kp = ksum + (size_t)bh*NCHUNK*64 + tid;
    for (int c = 0; c < NCHUNK; ++c) { const float t = kp[c*64]; kp[c*64] = rs; rs += t; }
  }
}

__global__ __launch_bounds__(256) void phaseC(const u16* __restrict__ Qb, const u16* __restrict__ Kb,
                                              const u16* __restrict__ Vb, const u16* __restrict__ Ast,
                                              const float* __restrict__ ksum, u16* __restrict__ Ob) {
  const int c = blockIdx.x, bh = blockIdx.y;
  const int b = bh >> 4, h = bh & 15;
  const int tid = threadIdx.x;
  const int wave = tid >> 6, lane = tid & 63, lr = lane & 15, g = lane >> 4;
  __shared__ u16 lS  [64*TS];
  __shared__ u16 lVt [64*TS];
  __shared__ u16 lKVt[64*TS];
  __shared__ float lks[64];
  __shared__ float lrs[64];
  __shared__ float lqk[64];
  const size_t mbase = (size_t)b*SEQ + (size_t)c*CHUNK;

  for (int s = tid; s < 512; s += 256) {
    const int t = s >> 3, dg = (s & 7) * 8;
    const bfrag8 vv = *(const bfrag8*)&Vb[(mbase + t)*DIM + h*64 + dg];
    #pragma unroll
    for (int j = 0; j < 8; ++j) lVt[(dg + j)*TS + t] = (u16)vv[j];
  }
  const u16* kvsrc = Ast + (((size_t)bh*NCHUNK + c) << 12);
  for (int s = tid; s < 512; s += 256) {
    const int e = s >> 3, dg = (s & 7) * 8;
    *(bfrag8*)&lKVt[e*TS + dg] = *(const bfrag8*)&kvsrc[e*64 + dg];
  }
  if (tid < 64) lks[tid] = ksum[((size_t)bh*NCHUNK + c)*64 + tid];

  bfrag8 qf[2], kf[4][2];
  {
    const u16* qrow = Qb + (mbase + wave*16 + lr)*DIM + h*64;
    qf[0] = *(const bfrag8*)&qrow[g*8];
    qf[1] = *(const bfrag8*)&qrow[32 + g*8];
  }
  #pragma unroll
  for (int j = 0; j < 4; ++j) {
    const u16* krow = Kb + (mbase + j*16 + lr)*DIM + h*64;
    kf[j][0] = *(const bfrag8*)&krow[g*8];
    kf[j][1] = *(const bfrag8*)&krow[32 + g*8];
  }

  facc4 accs[4] = {};
  #pragma unroll
  for (int kt = 0; kt < 2; ++kt)
    #pragma unroll
    for (int j = 0; j < 4; ++j)
      accs[j] = __builtin_amdgcn_mfma_f32_16x16x32_bf16(qf[kt], kf[j][kt], accs[j], 0, 0, 0);

  float rs[4] = {0.f, 0.f, 0.f, 0.f};
  #pragma unroll
  for (int j = 0; j < 4; ++j) {
    const int cc = j*16 + lr;
    #pragma unroll
    for (int r = 0; r < 4; ++r) {
      const int rr = wave*16 + g*4 + r;
      const float vS = (cc <= rr) ? accs[j][r] : 0.f;
      rs[r] += vS;
      lS[rr*TS + cc] = f2bf(vS);
    }
  }
  #pragma unroll
  for (int r = 0; r < 4; ++r) {
    float t = rs[r];
    t += __shfl_xor(t, 1, 64); t += __shfl_xor(t, 2, 64);
    t += __shfl_xor(t, 4, 64); t += __shfl_xor(t, 8, 64);
    if (lr == 0) lrs[wave*16 + g*4 + r] = t;
  }
  __syncthreads();

  {
    const u16* qr2 = Qb + (mbase + wave*16 + lr)*DIM + h*64 + g*16;
    const bfrag8 a0 = *(const bfrag8*)&qr2[0];
    const bfrag8 a1 = *(const bfrag8*)&qr2[8];
    float t = 0.f;
    #pragma unroll
    for (int j = 0; j < 8; ++j)
      t += bf2f((u16)a0[j]) * lks[g*16 + j] + bf2f((u16)a1[j]) * lks[g*16 + 8 + j];
    t += __shfl_xor(t, 16, 64);
    t += __shfl_xor(t, 32, 64);
    if (g == 0) lqk[wave*16 + lr] = t;
  }

  facc4 acco[4] = {};
  #pragma unroll
  for (int kt = 0; kt < 2; ++kt) {
    const bfrag8 sf = *(const bfrag8*)&lS[(wave*16 + lr)*TS + kt*32 + g*8];
    #pragma unroll
    for (int j = 0; j < 4; ++j) {
      const bfrag8 vf = *(const bfrag8*)&lVt[(j*16 + lr)*TS + kt*32 + g*8];
      acco[j] = __builtin_amdgcn_mfma_f32_16x16x32_bf16(sf, vf, acco[j], 0, 0, 0);
    }
  }
  #pragma unroll
  for (int kt = 0; kt < 2; ++kt)
    #pragma unroll
    for (int j = 0; j < 4; ++j) {
      const bfrag8 kvf = *(const bfrag8*)&lKVt[(j*16 + lr)*TS + kt*32 + g*8];
      acco[j] = __builtin_amdgcn_mfma_f32_16x16x32_bf16(qf[kt], kvf, acco[j], 0, 0, 0);
    }

  #pragma unroll
  for (int r = 0; r < 4; ++r) {
    const int rr = wave*16 + g*4 + r;
    const float rden = 1.0f / (lrs[rr] + lqk[rr] + 1e-6f);
    #pragma unroll
    for (int j = 0; j < 4; ++j)
      Ob[(mbase + rr)*DIM + h*64 + j*16 + lr] = f2bf(acco[j][r] * rden);
  }
}

// ---------------- launch ----------------
extern "C" void kernel_launch(void* const* d_in, const int* in_sizes, int n_in,
                              void* d_out, int out_size, void* d_ws, size_t ws_size,
                              hipStream_t stream) {
  const float* x    = (const float*)d_in[0];
  const float* Wq   = (const float*)d_in[1];
  const float* Wk   = (const float*)d_in[2];
  const float* Wv   = (const float*)d_in[3];
  const float* Wo   = (const float*)d_in[4];
  const float* proj = (const float*)d_in[5];
  float* out = (float*)d_out;

  char* ws = (char*)d_ws;
  u16*   xb   = (u16*)  (ws);                       // 16 MB : x in bf16
  u16*   wt   = (u16*)  (ws + 16777216);            //  8 MB : Wq',Wk',Wv^T,Wo^T bf16 (transposed)
  u16*   qkv  = (u16*)  (ws + 25165824);            // 48 MB : Q,K,V bf16 (post feature map)
  u16*   Ob   = (u16*)  (ws + 75497472);            // 16 MB : attention out bf16
  u16*   Ast  = (u16*)  (ws + 92274688);            // 16 MB : chunk KV states bf16 [e][d]
  float* ksum = (float*)(ws + 109051904);           // 512 KB : chunk k-sums fp32
  (void)ws_size; (void)in_sizes; (void)n_in; (void)out_size;

  conv_f32_bf16<<<dim3((MROWS*DIM)/1024), 256, 0, stream>>>(x, xb);
  fold_qk      <<<dim3(DIM/32, NH, 2), 256, 0, stream>>>(Wq, Wk, proj, wt);
  trans_conv   <<<dim3(DIM/32, DIM/32, 2), 256, 0, stream>>>(Wv, Wo, wt);

  // QKV fused: M=8192, N=3072 (wt rows 0..3071 = Wq'|Wk'|Wv^T); 768 blocks = 3 exact rounds
  gemmP<0><<<dim3(64*12), 512, 0, stream>>>(xb, wt, qkv, nullptr);

  const u16* Qb = qkv;
  const u16* Kb = qkv + (size_t)MROWS*DIM;
  const u16* Vb = qkv + 2*(size_t)MROWS*DIM;

  phaseA<<<dim3(NCHUNK, BH), 256, 0, stream>>>(Kb, Vb, Ast, ksum);
  phaseB<<<dim3(BH, 16), 256, 0, stream>>>(Ast, ksum);
  phaseC<<<dim3(NCHUNK, BH), 256, 0, stream>>>(Qb, Kb, Vb, Ast, ksum, Ob);

  // out GEMM: M=8192, N=1024; 256 blocks = 1 exact round
  gemmP<1><<<dim3(64*4), 512, 0, stream>>>(Ob, wt + 3*(size_t)DIM*DIM, nullptr, out);
}